// Round 5
// baseline (17.559 us; speedup 1.0000x reference)
//
#include <hip/hip_runtime.h>

#define NTOT 8192
#define NG   64
#define BT   1024          // 16 waves per block
#define NW   (BT / 64)     // 16 waves
#define QN   (NTOT / NW)   // elements scanned per wave (512)
#define CAP  64            // per-wave staging capacity (expected ~8, 64 = >19 sigma)
#define MAXM 512           // per-group capacity (expected ~128, 34 sigma)

// One block per group g (64 blocks x 1024 threads). Single fused kernel:
//  Phase A: each wave scans its 512-element slice with int4/float4 loads
//    (2 iterations, both loads issued up front); 4 ballots per chunk; stable
//    positions via earlier-lane popcounts + intra-lane prefix -> per-wave LDS.
//  Phase B: stitch to compact s_s[0..m); 1024 threads do the m(m-1)/2
//    softplus terms (row = tid&127, 8 column phases).
//  Phase C: block reduce -> partial[2g]=sum, partial[2g+1]=count; thread 0
//    release-increments a ticket; the last block (old==NG-1) acquire-reads
//    all partials in fixed order and writes out[0] = sum/count.
__global__ __launch_bounds__(BT) void rankloss_fused(
    const float* __restrict__ score, const int* __restrict__ gid,
    float* __restrict__ partial, unsigned* __restrict__ ticket,
    float* __restrict__ out)
{
  const int g    = blockIdx.x;
  const int tid  = threadIdx.x;
  const int wid  = tid >> 6;
  const int lane = tid & 63;

  __shared__ float s_stage[NW][CAP];
  __shared__ float s_s[MAXM];
  __shared__ int   s_wcnt[NW];
  __shared__ float s_red[NW];

  // ---- Phase A: single-pass vectorized stable compaction ----
  const unsigned long long below = (1ull << lane) - 1ull;
  const int qbase = wid * QN;
  int cnt = 0;
  #pragma unroll
  for (int it = 0; it < QN / 256; ++it) {          // 2 iterations
    const int e = qbase + it * 256 + lane * 4;     // 16B-aligned
    const int4   g4 = *reinterpret_cast<const int4*>(gid + e);
    const float4 s4 = *reinterpret_cast<const float4*>(score + e);
    const unsigned long long m0 = __ballot(g4.x == g);
    const unsigned long long m1 = __ballot(g4.y == g);
    const unsigned long long m2 = __ballot(g4.z == g);
    const unsigned long long m3 = __ballot(g4.w == g);
    int p = cnt + __popcll(m0 & below) + __popcll(m1 & below)
                + __popcll(m2 & below) + __popcll(m3 & below);
    if (g4.x == g) { if (p < CAP) s_stage[wid][p] = s4.x; ++p; }
    if (g4.y == g) { if (p < CAP) s_stage[wid][p] = s4.y; ++p; }
    if (g4.z == g) { if (p < CAP) s_stage[wid][p] = s4.z; ++p; }
    if (g4.w == g) { if (p < CAP) s_stage[wid][p] = s4.w; ++p; }
    cnt += __popcll(m0) + __popcll(m1) + __popcll(m2) + __popcll(m3);
  }
  if (lane == 0) s_wcnt[wid] = cnt;
  __syncthreads();

  int base = 0, m = 0;
  #pragma unroll
  for (int w = 0; w < NW; ++w) {
    const int c = s_wcnt[w];
    base += (w < wid) ? c : 0;
    m += c;
  }
  for (int t = lane; t < cnt; t += 64) s_s[base + t] = s_stage[wid][t];
  __syncthreads();

  // ---- Phase B: pairwise softplus over compact LDS array ----
  float sum = 0.f;
  const int cphase = tid >> 7;                     // 0..7
  for (int a = (tid & 127); a < m; a += 128) {
    const float sa = s_s[a];
    for (int b = a + 1 + cphase; b < m; b += 8) {
      const float x = s_s[b] - sa;                 // s_j - s_i, j > i
      sum += fmaxf(x, 0.f) + __logf(1.f + __expf(-fabsf(x)));
    }
  }

  // ---- Phase C: block reduce, per-group partial, last-block finalize ----
  for (int off = 32; off > 0; off >>= 1) sum += __shfl_down(sum, off, 64);
  if (lane == 0) s_red[wid] = sum;
  __syncthreads();
  if (tid == 0) {
    float ts = 0.f;
    #pragma unroll
    for (int w = 0; w < NW; ++w) ts += s_red[w];
    partial[2 * g]     = ts;
    partial[2 * g + 1] = 0.5f * (float)m * (float)(m - 1);
    // release our partial writes, acquire everyone else's
    const unsigned old = __hip_atomic_fetch_add(ticket, 1u, __ATOMIC_ACQ_REL,
                                                __HIP_MEMORY_SCOPE_AGENT);
    if (old == NG - 1) {
      float s = 0.f, c = 0.f;
      #pragma unroll 8
      for (int k = 0; k < NG / 2; ++k) {           // fixed order: deterministic
        const float4 p4 = reinterpret_cast<const float4*>(partial)[k];
        s += p4.x + p4.z;
        c += p4.y + p4.w;
      }
      out[0] = s / c;
    }
  }
}

extern "C" void kernel_launch(void* const* d_in, const int* in_sizes, int n_in,
                              void* d_out, int out_size, void* d_ws, size_t ws_size,
                              hipStream_t stream) {
  const float* score   = (const float*)d_in[0];
  const int*   gid     = (const int*)d_in[1];
  float*       partial = (float*)d_ws;                 // 128 floats
  unsigned*    ticket  = (unsigned*)((char*)d_ws + 512);

  hipMemsetAsync(ticket, 0, sizeof(unsigned), stream);
  rankloss_fused<<<NG, BT, 0, stream>>>(score, gid, partial, ticket,
                                        (float*)d_out);
}

// Round 6
// 12.653 us; speedup vs baseline: 1.3877x; 1.3877x over previous
//
#include <hip/hip_runtime.h>

#define NTOT 8192
#define NG   64
#define BT   1024          // 16 waves per block
#define NW   (BT / 64)     // 16 waves
#define QN   (NTOT / NW)   // elements scanned per wave (512)
#define CAP  64            // per-wave staging capacity (expected ~8, 64 = >19 sigma)
#define MAXM 512           // per-group capacity (expected ~128, 34 sigma)

// One block per group g (64 blocks x 1024 threads).
//  Phase A: each wave scans its 512-element slice with int4/float4 loads
//    (2 iterations, both loads issued up front); 4 ballots per chunk; stable
//    positions via earlier-lane popcounts + intra-lane prefix -> per-wave LDS.
//  Phase B: stitch to compact s_s[0..m); 1024 threads do the m(m-1)/2
//    softplus terms (row = tid&127, 8 column phases).
//  Phase C: block reduce -> partial[2g]=sum, partial[2g+1]=count.
__global__ __launch_bounds__(BT) void rankloss_grouped(
    const float* __restrict__ score, const int* __restrict__ gid,
    float* __restrict__ partial)
{
  const int g    = blockIdx.x;
  const int tid  = threadIdx.x;
  const int wid  = tid >> 6;
  const int lane = tid & 63;

  __shared__ float s_stage[NW][CAP];
  __shared__ float s_s[MAXM];
  __shared__ int   s_wcnt[NW];
  __shared__ float s_red[NW];

  // ---- Phase A: single-pass vectorized stable compaction ----
  const unsigned long long below = (1ull << lane) - 1ull;
  const int qbase = wid * QN;
  int cnt = 0;
  #pragma unroll
  for (int it = 0; it < QN / 256; ++it) {          // 2 iterations
    const int e = qbase + it * 256 + lane * 4;     // 16B-aligned
    const int4   g4 = *reinterpret_cast<const int4*>(gid + e);
    const float4 s4 = *reinterpret_cast<const float4*>(score + e);
    const unsigned long long m0 = __ballot(g4.x == g);
    const unsigned long long m1 = __ballot(g4.y == g);
    const unsigned long long m2 = __ballot(g4.z == g);
    const unsigned long long m3 = __ballot(g4.w == g);
    int p = cnt + __popcll(m0 & below) + __popcll(m1 & below)
                + __popcll(m2 & below) + __popcll(m3 & below);
    if (g4.x == g) { if (p < CAP) s_stage[wid][p] = s4.x; ++p; }
    if (g4.y == g) { if (p < CAP) s_stage[wid][p] = s4.y; ++p; }
    if (g4.z == g) { if (p < CAP) s_stage[wid][p] = s4.z; ++p; }
    if (g4.w == g) { if (p < CAP) s_stage[wid][p] = s4.w; ++p; }
    cnt += __popcll(m0) + __popcll(m1) + __popcll(m2) + __popcll(m3);
  }
  if (lane == 0) s_wcnt[wid] = cnt;
  __syncthreads();

  int base = 0, m = 0;
  #pragma unroll
  for (int w = 0; w < NW; ++w) {
    const int c = s_wcnt[w];
    base += (w < wid) ? c : 0;
    m += c;
  }
  for (int t = lane; t < cnt; t += 64) s_s[base + t] = s_stage[wid][t];
  __syncthreads();

  // ---- Phase B: pairwise softplus over compact LDS array ----
  float sum = 0.f;
  const int cphase = tid >> 7;                     // 0..7
  for (int a = (tid & 127); a < m; a += 128) {
    const float sa = s_s[a];
    for (int b = a + 1 + cphase; b < m; b += 8) {
      const float x = s_s[b] - sa;                 // s_j - s_i, j > i
      sum += fmaxf(x, 0.f) + __logf(1.f + __expf(-fabsf(x)));
    }
  }

  // ---- Phase C: block reduce, write per-group partial ----
  for (int off = 32; off > 0; off >>= 1) sum += __shfl_down(sum, off, 64);
  if (lane == 0) s_red[wid] = sum;
  __syncthreads();
  if (tid == 0) {
    float ts = 0.f;
    #pragma unroll
    for (int w = 0; w < NW; ++w) ts += s_red[w];
    partial[2 * g]     = ts;
    partial[2 * g + 1] = 0.5f * (float)m * (float)(m - 1);
  }
}

// 64 partials -> scalar mean; exactly one wave.
__global__ void rankloss_final(const float* __restrict__ partial, float* __restrict__ out) {
  const int lane = threadIdx.x;
  float s = partial[2 * lane];
  float c = partial[2 * lane + 1];
  for (int off = 32; off > 0; off >>= 1) {
    s += __shfl_down(s, off, 64);
    c += __shfl_down(c, off, 64);
  }
  if (lane == 0) out[0] = s / c;
}

extern "C" void kernel_launch(void* const* d_in, const int* in_sizes, int n_in,
                              void* d_out, int out_size, void* d_ws, size_t ws_size,
                              hipStream_t stream) {
  const float* score   = (const float*)d_in[0];
  const int*   gid     = (const int*)d_in[1];
  float*       partial = (float*)d_ws;   // 128 floats, fully rewritten each call

  rankloss_grouped<<<NG, BT, 0, stream>>>(score, gid, partial);
  rankloss_final<<<1, 64, 0, stream>>>(partial, (float*)d_out);
}

// Round 7
// 12.045 us; speedup vs baseline: 1.4577x; 1.0505x over previous
//
#include <hip/hip_runtime.h>

#define NTOT 8192
#define NG   64
#define BT   1024          // 16 waves per block
#define NW   (BT / 64)     // 16 waves
#define QN   (NTOT / NW)   // elements scanned per wave (512)
#define CAP  64            // per-wave staging capacity (expected ~8, 64 = >19 sigma)
#define MAXM 512           // per-group capacity (expected ~128, 34 sigma)

// One block per group g (64 blocks x 1024 threads).
//  Phase A: each wave scans its 512-element slice with int4/float4 loads
//    (2 iterations, both loads issued up front); 4 ballots per chunk; stable
//    positions via earlier-lane popcounts + intra-lane prefix -> per-wave LDS.
//  Phase B: stitch to compact s_s[0..m); 1024 threads over (row = tid&63
//    step 64, 16 column phases) -> worst serial softplus chain ~12.
//  Phase C: wave shuffle reduce -> cross-wave shuffle reduce -> float2 store.
__global__ __launch_bounds__(BT) void rankloss_grouped(
    const float* __restrict__ score, const int* __restrict__ gid,
    float* __restrict__ partial)
{
  const int g    = blockIdx.x;
  const int tid  = threadIdx.x;
  const int wid  = tid >> 6;
  const int lane = tid & 63;

  __shared__ float s_stage[NW][CAP];
  __shared__ float s_s[MAXM];
  __shared__ int   s_wcnt[NW];
  __shared__ float s_red[NW];

  // ---- Phase A: single-pass vectorized stable compaction ----
  const unsigned long long below = (1ull << lane) - 1ull;
  const int qbase = wid * QN;
  int cnt = 0;
  #pragma unroll
  for (int it = 0; it < QN / 256; ++it) {          // 2 iterations
    const int e = qbase + it * 256 + lane * 4;     // 16B-aligned
    const int4   g4 = *reinterpret_cast<const int4*>(gid + e);
    const float4 s4 = *reinterpret_cast<const float4*>(score + e);
    const unsigned long long m0 = __ballot(g4.x == g);
    const unsigned long long m1 = __ballot(g4.y == g);
    const unsigned long long m2 = __ballot(g4.z == g);
    const unsigned long long m3 = __ballot(g4.w == g);
    int p = cnt + __popcll(m0 & below) + __popcll(m1 & below)
                + __popcll(m2 & below) + __popcll(m3 & below);
    if (g4.x == g) { if (p < CAP) s_stage[wid][p] = s4.x; ++p; }
    if (g4.y == g) { if (p < CAP) s_stage[wid][p] = s4.y; ++p; }
    if (g4.z == g) { if (p < CAP) s_stage[wid][p] = s4.z; ++p; }
    if (g4.w == g) { if (p < CAP) s_stage[wid][p] = s4.w; ++p; }
    cnt += __popcll(m0) + __popcll(m1) + __popcll(m2) + __popcll(m3);
  }
  if (lane == 0) s_wcnt[wid] = cnt;
  __syncthreads();

  int base = 0, m = 0;
  #pragma unroll
  for (int w = 0; w < NW; ++w) {
    const int c = s_wcnt[w];
    base += (w < wid) ? c : 0;
    m += c;
  }
  for (int t = lane; t < cnt; t += 64) s_s[base + t] = s_stage[wid][t];
  __syncthreads();

  // ---- Phase B: pairwise softplus over compact LDS array ----
  // row a = tid&63 (step 64), column phase ph = tid>>6 (16 phases, step 16)
  float sum = 0.f;
  const int ph = tid >> 6;                         // 0..15
  for (int a = (tid & 63); a < m; a += 64) {
    const float sa = s_s[a];
    for (int b = a + 1 + ph; b < m; b += 16) {
      const float x = s_s[b] - sa;                 // s_j - s_i, j > i
      sum += fmaxf(x, 0.f) + __logf(1.f + __expf(-fabsf(x)));
    }
  }

  // ---- Phase C: wave reduce -> cross-wave shuffle reduce -> float2 store ----
  #pragma unroll
  for (int off = 32; off > 0; off >>= 1) sum += __shfl_down(sum, off, 64);
  if (lane == 0) s_red[wid] = sum;
  __syncthreads();
  if (tid < 64) {
    float v = (tid < NW) ? s_red[tid] : 0.f;
    #pragma unroll
    for (int off = 8; off > 0; off >>= 1) v += __shfl_down(v, off, 64);
    if (tid == 0) {
      float2 pw;
      pw.x = v;
      pw.y = 0.5f * (float)m * (float)(m - 1);
      reinterpret_cast<float2*>(partial)[g] = pw;
    }
  }
}

// 64 (sum,count) float2 partials -> scalar mean; exactly one wave.
__global__ void rankloss_final(const float* __restrict__ partial, float* __restrict__ out) {
  const int lane = threadIdx.x;
  const float2 p = reinterpret_cast<const float2*>(partial)[lane];
  float s = p.x;
  float c = p.y;
  #pragma unroll
  for (int off = 32; off > 0; off >>= 1) {
    s += __shfl_down(s, off, 64);
    c += __shfl_down(c, off, 64);
  }
  if (lane == 0) out[0] = s / c;
}

extern "C" void kernel_launch(void* const* d_in, const int* in_sizes, int n_in,
                              void* d_out, int out_size, void* d_ws, size_t ws_size,
                              hipStream_t stream) {
  const float* score   = (const float*)d_in[0];
  const int*   gid     = (const int*)d_in[1];
  float*       partial = (float*)d_ws;   // 64 float2, fully rewritten each call

  rankloss_grouped<<<NG, BT, 0, stream>>>(score, gid, partial);
  rankloss_final<<<1, 64, 0, stream>>>(partial, (float*)d_out);
}